// Round 1
// baseline (745.197 us; speedup 1.0000x reference)
//
#include <hip/hip_runtime.h>
#include <math.h>

#define NR 4096
#define NS 768
#define HID 64

// Outputs (flat, fp32): depth[4096] | image[4096*2] | wsum[4096] | weights[4096*768] | z_vals[4096*768]
#define OFF_IMAGE   (NR)
#define OFF_WSUM    (NR*3)
#define OFF_WEIGHTS (NR*4)
#define OFF_ZVALS   (NR*4 + NR*NS)

__device__ __forceinline__ float reluf(float x){ return fmaxf(x, 0.0f); }

// One thread per sample. idx = n*NS + s  => each wave64 has uniform n (uniform
// ray + weight loads -> scalar path) and consecutive s (coalesced writes).
__global__ __launch_bounds__(256) void mlp_kernel(
    const float* __restrict__ rays_o, const float* __restrict__ rays_d,
    const float* __restrict__ timev,
    const float* __restrict__ W1, const float* __restrict__ b1,
    const float* __restrict__ W2, const float* __restrict__ b2,
    const float* __restrict__ w_sig, const float* __restrict__ b_sig,
    const float* __restrict__ Wc1, const float* __restrict__ bc1,
    const float* __restrict__ Wc2, const float* __restrict__ bc2,
    float* __restrict__ alpha_out,   // [NR][NS]  (aliases the weights slot of d_out)
    float* __restrict__ rgb_out)     // [NR][NS][2] in d_ws
{
    int idx = blockIdx.x * 256 + threadIdx.x;   // 0 .. NR*NS-1
    int n = idx / NS;
    int s = idx - n * NS;

    float z = 0.01f + 0.8f * ((float)s * (1.0f/767.0f));

    float ox = rays_o[3*n+0], oy = rays_o[3*n+1], oz = rays_o[3*n+2];
    float dx = rays_d[3*n+0], dy = rays_d[3*n+1], dz = rays_d[3*n+2];
    float t  = timev[n];

    float x = fminf(fmaxf(fmaf(dx, z, ox), -1.0f), 1.0f);
    float y = fminf(fmaxf(fmaf(dy, z, oy), -1.0f), 1.0f);
    float w = fminf(fmaf(dz, z, oz) > 1.0f ? 1.0f : fmaf(dz, z, oz), -1.0f) > 1.0f ? 1.0f : fmaxf(fminf(fmaf(dz, z, oz), 1.0f), -1.0f);
    // (simple clamp; rewrite clearly)
    w = fminf(fmaxf(fmaf(dz, z, oz), -1.0f), 1.0f);

    // layer 1: 4 -> 64, relu
    float h1[HID];
    #pragma unroll
    for (int j = 0; j < HID; ++j) {
        float a = b1[j];
        a = fmaf(x, W1[0*HID + j], a);
        a = fmaf(y, W1[1*HID + j], a);
        a = fmaf(w, W1[2*HID + j], a);
        a = fmaf(t, W1[3*HID + j], a);
        h1[j] = reluf(a);
    }

    // layer 2: 64 -> 64, relu
    float h2[HID];
    #pragma unroll
    for (int j = 0; j < HID; ++j) {
        float a = b2[j];
        #pragma unroll
        for (int k = 0; k < HID; ++k) a = fmaf(h1[k], W2[k*HID + j], a);
        h2[j] = reluf(a);
    }

    // sigma head: 64 -> 1, softplus
    float sa = b_sig[0];
    #pragma unroll
    for (int k = 0; k < HID; ++k) sa = fmaf(h2[k], w_sig[k], sa);
    float sigma = fmaxf(sa, 0.0f) + log1pf(expf(-fabsf(sa)));

    // color layer 1: 67 -> 64, relu
    float c[HID];
    #pragma unroll
    for (int j = 0; j < HID; ++j) {
        float a = bc1[j];
        a = fmaf(dx, Wc1[0*HID + j], a);
        a = fmaf(dy, Wc1[1*HID + j], a);
        a = fmaf(dz, Wc1[2*HID + j], a);
        #pragma unroll
        for (int k = 0; k < HID; ++k) a = fmaf(h2[k], Wc1[(3+k)*HID + j], a);
        c[j] = reluf(a);
    }

    // color layer 2: 64 -> 2, sigmoid
    float r0 = bc2[0], r1 = bc2[1];
    #pragma unroll
    for (int k = 0; k < HID; ++k) {
        r0 = fmaf(c[k], Wc2[2*k + 0], r0);
        r1 = fmaf(c[k], Wc2[2*k + 1], r1);
    }
    r0 = 1.0f / (1.0f + expf(-r0));
    r1 = 1.0f / (1.0f + expf(-r1));

    // alpha from sigma (DENSITY_SCALE = 1)
    float delta = (s < NS-1) ? (0.8f/767.0f) : (0.8f/768.0f);
    float alpha = 1.0f - expf(-delta * sigma);

    alpha_out[idx]     = alpha;
    rgb_out[2*idx + 0] = r0;
    rgb_out[2*idx + 1] = r1;
}

// Wave-per-ray compositing: 12 chunks of 64 steps; Hillis-Steele prefix
// product of (1 - alpha + 1e-15) per chunk, carry T across chunks.
__global__ __launch_bounds__(256) void composite_kernel(
    const float* __restrict__ rgb,   // [NR][NS][2]
    float* __restrict__ out)
{
    int gtid = blockIdx.x * 256 + threadIdx.x;
    int ray  = gtid >> 6;
    int lane = threadIdx.x & 63;
    if (ray >= NR) return;

    float* __restrict__ depth_o = out;
    float* __restrict__ image_o = out + OFF_IMAGE;
    float* __restrict__ wsum_o  = out + OFF_WSUM;
    float* __restrict__ w_o     = out + OFF_WEIGHTS;   // alpha in, weights out
    float* __restrict__ z_o     = out + OFF_ZVALS;

    float T = 1.0f;
    float depth = 0.0f, wsum = 0.0f, im0 = 0.0f, im1 = 0.0f;

    for (int ch = 0; ch < NS/64; ++ch) {
        int s   = ch*64 + lane;
        int idx = ray*NS + s;
        float a  = w_o[idx];
        float zv = 0.01f + 0.8f * ((float)s * (1.0f/767.0f));
        float f  = 1.0f - a + 1e-15f;

        // inclusive prefix product of f within the wave
        float p = f;
        #pragma unroll
        for (int off = 1; off < 64; off <<= 1) {
            float v = __shfl_up(p, off, 64);
            if (lane >= off) p *= v;
        }
        float excl = __shfl_up(p, 1, 64);
        if (lane == 0) excl = 1.0f;

        float wgt = a * T * excl;

        float r0 = rgb[2*idx + 0], r1 = rgb[2*idx + 1];
        depth = fmaf(wgt, zv, depth);
        wsum += wgt;
        im0   = fmaf(wgt, r0, im0);
        im1   = fmaf(wgt, r1, im1);

        w_o[idx] = wgt;
        z_o[idx] = zv;

        T *= __shfl(p, 63, 64);
    }

    #pragma unroll
    for (int off = 32; off >= 1; off >>= 1) {
        depth += __shfl_down(depth, off, 64);
        wsum  += __shfl_down(wsum , off, 64);
        im0   += __shfl_down(im0  , off, 64);
        im1   += __shfl_down(im1  , off, 64);
    }
    if (lane == 0) {
        depth_o[ray]      = depth;
        image_o[2*ray+0]  = im0;
        image_o[2*ray+1]  = im1;
        wsum_o[ray]       = wsum;
    }
}

extern "C" void kernel_launch(void* const* d_in, const int* in_sizes, int n_in,
                              void* d_out, int out_size, void* d_ws, size_t ws_size,
                              hipStream_t stream) {
    const float* rays_o = (const float*)d_in[0];
    const float* rays_d = (const float*)d_in[1];
    const float* timev  = (const float*)d_in[2];
    const float* W1     = (const float*)d_in[3];
    const float* b1     = (const float*)d_in[4];
    const float* W2     = (const float*)d_in[5];
    const float* b2     = (const float*)d_in[6];
    const float* w_sig  = (const float*)d_in[7];
    const float* b_sig  = (const float*)d_in[8];
    const float* Wc1    = (const float*)d_in[9];
    const float* bc1    = (const float*)d_in[10];
    const float* Wc2    = (const float*)d_in[11];
    const float* bc2    = (const float*)d_in[12];

    float* out   = (float*)d_out;
    float* alpha = out + OFF_WEIGHTS;      // stash alpha in the weights slot
    float* rgb   = (float*)d_ws;           // [NR][NS][2] = 25.2 MB scratch

    dim3 blk(256);
    dim3 grid_mlp((NR*NS)/256);
    hipLaunchKernelGGL(mlp_kernel, grid_mlp, blk, 0, stream,
                       rays_o, rays_d, timev, W1, b1, W2, b2, w_sig, b_sig,
                       Wc1, bc1, Wc2, bc2, alpha, rgb);

    dim3 grid_cmp((NR*64)/256);
    hipLaunchKernelGGL(composite_kernel, grid_cmp, blk, 0, stream, rgb, out);
}

// Round 5
// 193.333 us; speedup vs baseline: 3.8545x; 3.8545x over previous
//
#include <hip/hip_runtime.h>
#include <hip/hip_bf16.h>
#include <math.h>

#define NR 4096
#define NS 768

// Outputs (flat, fp32): depth[4096] | image[4096*2] | wsum[4096] | weights[4096*768] | z_vals[4096*768]
#define OFF_IMAGE   (NR)
#define OFF_WSUM    (NR*3)
#define OFF_WEIGHTS (NR*4)
#define OFF_ZVALS   (NR*4 + NR*NS)

typedef short bf16x8 __attribute__((ext_vector_type(8)));
typedef float f32x4  __attribute__((ext_vector_type(4)));

static __device__ __forceinline__ unsigned cvt_pk_bf16(float a, float b){
    unsigned r;
    asm("v_cvt_pk_bf16_f32 %0, %1, %2" : "=v"(r) : "v"(a), "v"(b));
    return r;
}
static __device__ __forceinline__ float bf2f(unsigned short h){
    return __builtin_bit_cast(float, ((unsigned)h) << 16);
}
static __device__ __forceinline__ f32x4 splat4(float v){ f32x4 r = {v,v,v,v}; return r; }

// ---------------------------------------------------------------------------
// Kernel 1: per-sample MLP via bf16 MFMA. One wave = 64 samples = 1 ray x 64
// steps (ray data wave-uniform). LDS tile [64 rows][64 bf16], 16B chunks
// XOR-swizzled by row&7 so ds_read_b128 column-slices are conflict-free.
// ---------------------------------------------------------------------------
__global__ __launch_bounds__(256, 2) void mlp_mfma_kernel(
    const float* __restrict__ rays_o, const float* __restrict__ rays_d,
    const float* __restrict__ timev,
    const float* __restrict__ W1, const float* __restrict__ b1,
    const float* __restrict__ W2, const float* __restrict__ b2,
    const float* __restrict__ w_sig, const float* __restrict__ b_sig,
    const float* __restrict__ Wc1, const float* __restrict__ bc1,
    const float* __restrict__ Wc2, const float* __restrict__ bc2,
    float* __restrict__ alpha_out,   // [NR*NS] (aliases weights slot of d_out)
    float* __restrict__ rgb_out)     // [NR*NS][2] in d_ws
{
    __shared__ __align__(16) unsigned short lds[4][64*64];
    const int wid  = threadIdx.x >> 6;
    const int lane = threadIdx.x & 63;
    const int g = lane >> 4;          // 0..3
    const int c = lane & 15;          // 0..15
    unsigned short* L = &lds[wid][0];

    // ---- build bf16 B-fragments (weights), k-indexing: elem i <-> k0+i ----
    auto ldfrag = [&](const float* __restrict__ W, int k0, int col, int kmax)->bf16x8 {
        union { bf16x8 v; unsigned u[4]; } r;
        #pragma unroll
        for (int p = 0; p < 4; ++p) {
            int k = k0 + 2*p;
            float a = (k     < kmax) ? W[k*64 + col]     : 0.f;
            float b = (k + 1 < kmax) ? W[(k+1)*64 + col] : 0.f;
            r.u[p] = cvt_pk_bf16(a, b);
        }
        return r.v;
    };

    bf16x8 bW1[4], bW2[2][4], bWc1[2][4];
    float  b1c[4], b2c[4], bc1c[4], wdir[3][4];
    #pragma unroll
    for (int nt = 0; nt < 4; ++nt) {
        int col = nt*16 + c;
        bW1[nt] = ldfrag(W1, 8*g, col, 4);
        #pragma unroll
        for (int kt = 0; kt < 2; ++kt) {
            bW2[kt][nt]  = ldfrag(W2,        kt*32 + 8*g, col, 64);
            bWc1[kt][nt] = ldfrag(Wc1 + 3*64, kt*32 + 8*g, col, 64);  // h-part rows 3..66
        }
        b1c[nt]  = b1[col];
        b2c[nt]  = b2[col];
        bc1c[nt] = bc1[col];
        #pragma unroll
        for (int d = 0; d < 3; ++d) wdir[d][nt] = Wc1[d*64 + col];    // dir rows 0..2
    }

    const int gwave = blockIdx.x*4 + wid;

    #pragma unroll 1
    for (int tt = 0; tt < 6; ++tt) {
        const int tile = gwave*6 + tt;          // 0..49151
        const int n  = tile / 12;               // ray (wave-uniform)
        const int s0 = (tile - n*12) * 64;
        const int s  = s0 + lane;

        const float z  = 0.01f + 0.8f * ((float)s * (1.0f/767.0f));
        const float ox = rays_o[3*n+0], oy = rays_o[3*n+1], oz = rays_o[3*n+2];
        const float dx = rays_d[3*n+0], dy = rays_d[3*n+1], dz = rays_d[3*n+2];
        const float tm = timev[n];

        const float px = fminf(fmaxf(fmaf(dx, z, ox), -1.f), 1.f);
        const float py = fminf(fmaxf(fmaf(dy, z, oy), -1.f), 1.f);
        const float pz = fminf(fmaxf(fmaf(dz, z, oz), -1.f), 1.f);

        // ---------------- GEMM1: [64,4(pad32)] @ W1 -> h1 ----------------
        const unsigned p01 = cvt_pk_bf16(px, py);
        const unsigned p23 = cvt_pk_bf16(pz, tm);
        f32x4 acc[4][4];
        #pragma unroll
        for (int mt = 0; mt < 4; ++mt) {
            int src = mt*16 + c;                       // sample-in-tile = A row
            unsigned q0 = (unsigned)__shfl((int)p01, src);
            unsigned q1 = (unsigned)__shfl((int)p23, src);
            union { bf16x8 v; unsigned u[4]; } a;
            a.u[0] = (g == 0) ? q0 : 0u;
            a.u[1] = (g == 0) ? q1 : 0u;
            a.u[2] = 0u; a.u[3] = 0u;
            #pragma unroll
            for (int nt = 0; nt < 4; ++nt)
                acc[mt][nt] = __builtin_amdgcn_mfma_f32_16x16x32_bf16(
                    a.v, bW1[nt], splat4(b1c[nt]), 0, 0, 0);
        }
        // relu + store h1 bf16 to LDS (swizzled)
        #pragma unroll
        for (int mt = 0; mt < 4; ++mt)
            #pragma unroll
            for (int nt = 0; nt < 4; ++nt)
                #pragma unroll
                for (int r = 0; r < 4; ++r) {
                    float v = fmaxf(acc[mt][nt][r], 0.f);
                    int row = mt*16 + g*4 + r, col = nt*16 + c;
                    L[row*64 + ((((col>>3) ^ (row&7))<<3) + (col&7))] =
                        (unsigned short)cvt_pk_bf16(v, 0.f);
                }

        // ---------------- GEMM2: h1 @ W2 -> h2 ----------------
        auto rdfrag = [&](int mt, int kt)->bf16x8 {
            int row = mt*16 + c;
            int chk = (kt*4 + g) ^ (row & 7);
            return *reinterpret_cast<const bf16x8*>(&L[row*64 + (chk<<3)]);
        };
        #pragma unroll
        for (int mt = 0; mt < 4; ++mt) {
            bf16x8 a0 = rdfrag(mt, 0), a1 = rdfrag(mt, 1);
            #pragma unroll
            for (int nt = 0; nt < 4; ++nt) {
                f32x4 t0 = __builtin_amdgcn_mfma_f32_16x16x32_bf16(a0, bW2[0][nt], splat4(b2c[nt]), 0,0,0);
                acc[mt][nt] = __builtin_amdgcn_mfma_f32_16x16x32_bf16(a1, bW2[1][nt], t0, 0,0,0);
            }
        }
        // relu + store h2 (overwrites h1 region)
        #pragma unroll
        for (int mt = 0; mt < 4; ++mt)
            #pragma unroll
            for (int nt = 0; nt < 4; ++nt)
                #pragma unroll
                for (int r = 0; r < 4; ++r) {
                    float v = fmaxf(acc[mt][nt][r], 0.f);
                    int row = mt*16 + g*4 + r, col = nt*16 + c;
                    L[row*64 + ((((col>>3) ^ (row&7))<<3) + (col&7))] =
                        (unsigned short)cvt_pk_bf16(v, 0.f);
                }

        // ---------------- sigma head (thread-per-sample from LDS) ----------
        float sg = b_sig[0];
        #pragma unroll
        for (int j = 0; j < 8; ++j) {
            int chk = j ^ (lane & 7);
            union { bf16x8 v; unsigned short us[8]; } hv;
            hv.v = *reinterpret_cast<const bf16x8*>(&L[lane*64 + (chk<<3)]);
            #pragma unroll
            for (int e = 0; e < 8; ++e)
                sg = fmaf(bf2f(hv.us[e]), w_sig[j*8+e], sg);
        }
        float sigma = fmaxf(sg, 0.f) + log1pf(expf(-fabsf(sg)));
        float delta = (s < NS-1) ? (0.8f/767.0f) : (0.8f/768.0f);
        alpha_out[tile*64 + lane] = 1.0f - expf(-delta * sigma);

        // ---------------- GEMM3: [dirs|h2] @ Wc1 -> cfeat ------------------
        float cinit[4];
        #pragma unroll
        for (int nt = 0; nt < 4; ++nt)
            cinit[nt] = fmaf(dx, wdir[0][nt], fmaf(dy, wdir[1][nt],
                        fmaf(dz, wdir[2][nt], bc1c[nt])));
        #pragma unroll
        for (int mt = 0; mt < 4; ++mt) {
            bf16x8 a0 = rdfrag(mt, 0), a1 = rdfrag(mt, 1);
            #pragma unroll
            for (int nt = 0; nt < 4; ++nt) {
                f32x4 t0 = __builtin_amdgcn_mfma_f32_16x16x32_bf16(a0, bWc1[0][nt], splat4(cinit[nt]), 0,0,0);
                acc[mt][nt] = __builtin_amdgcn_mfma_f32_16x16x32_bf16(a1, bWc1[1][nt], t0, 0,0,0);
            }
        }
        // relu + store cfeat (overwrites h2 after all reads)
        #pragma unroll
        for (int mt = 0; mt < 4; ++mt)
            #pragma unroll
            for (int nt = 0; nt < 4; ++nt)
                #pragma unroll
                for (int r = 0; r < 4; ++r) {
                    float v = fmaxf(acc[mt][nt][r], 0.f);
                    int row = mt*16 + g*4 + r, col = nt*16 + c;
                    L[row*64 + ((((col>>3) ^ (row&7))<<3) + (col&7))] =
                        (unsigned short)cvt_pk_bf16(v, 0.f);
                }

        // ---------------- rgb head ----------------
        float r0 = bc2[0], r1 = bc2[1];
        #pragma unroll
        for (int j = 0; j < 8; ++j) {
            int chk = j ^ (lane & 7);
            union { bf16x8 v; unsigned short us[8]; } hv;
            hv.v = *reinterpret_cast<const bf16x8*>(&L[lane*64 + (chk<<3)]);
            #pragma unroll
            for (int e = 0; e < 8; ++e) {
                float f = bf2f(hv.us[e]);
                int k = j*8 + e;
                r0 = fmaf(f, Wc2[2*k+0], r0);
                r1 = fmaf(f, Wc2[2*k+1], r1);
            }
        }
        r0 = 1.0f / (1.0f + expf(-r0));
        r1 = 1.0f / (1.0f + expf(-r1));
        *reinterpret_cast<float2*>(&rgb_out[2*(tile*64 + lane)]) = make_float2(r0, r1);
    }
}

// ---------------------------------------------------------------------------
// Kernel 2: wave-per-ray compositing (unchanged from round 1, proven correct)
// ---------------------------------------------------------------------------
__global__ __launch_bounds__(256) void composite_kernel(
    const float* __restrict__ rgb,   // [NR][NS][2]
    float* __restrict__ out)
{
    int gtid = blockIdx.x * 256 + threadIdx.x;
    int ray  = gtid >> 6;
    int lane = threadIdx.x & 63;
    if (ray >= NR) return;

    float* __restrict__ depth_o = out;
    float* __restrict__ image_o = out + OFF_IMAGE;
    float* __restrict__ wsum_o  = out + OFF_WSUM;
    float* __restrict__ w_o     = out + OFF_WEIGHTS;   // alpha in, weights out
    float* __restrict__ z_o     = out + OFF_ZVALS;

    float T = 1.0f;
    float depth = 0.0f, wsum = 0.0f, im0 = 0.0f, im1 = 0.0f;

    for (int ch = 0; ch < NS/64; ++ch) {
        int s   = ch*64 + lane;
        int idx = ray*NS + s;
        float a  = w_o[idx];
        float zv = 0.01f + 0.8f * ((float)s * (1.0f/767.0f));
        float f  = 1.0f - a + 1e-15f;

        float p = f;
        #pragma unroll
        for (int off = 1; off < 64; off <<= 1) {
            float v = __shfl_up(p, off, 64);
            if (lane >= off) p *= v;
        }
        float excl = __shfl_up(p, 1, 64);
        if (lane == 0) excl = 1.0f;

        float wgt = a * T * excl;

        float r0 = rgb[2*idx + 0], r1 = rgb[2*idx + 1];
        depth = fmaf(wgt, zv, depth);
        wsum += wgt;
        im0   = fmaf(wgt, r0, im0);
        im1   = fmaf(wgt, r1, im1);

        w_o[idx] = wgt;
        z_o[idx] = zv;

        T *= __shfl(p, 63, 64);
    }

    #pragma unroll
    for (int off = 32; off >= 1; off >>= 1) {
        depth += __shfl_down(depth, off, 64);
        wsum  += __shfl_down(wsum , off, 64);
        im0   += __shfl_down(im0  , off, 64);
        im1   += __shfl_down(im1  , off, 64);
    }
    if (lane == 0) {
        depth_o[ray]      = depth;
        image_o[2*ray+0]  = im0;
        image_o[2*ray+1]  = im1;
        wsum_o[ray]       = wsum;
    }
}

extern "C" void kernel_launch(void* const* d_in, const int* in_sizes, int n_in,
                              void* d_out, int out_size, void* d_ws, size_t ws_size,
                              hipStream_t stream) {
    const float* rays_o = (const float*)d_in[0];
    const float* rays_d = (const float*)d_in[1];
    const float* timev  = (const float*)d_in[2];
    const float* W1     = (const float*)d_in[3];
    const float* b1     = (const float*)d_in[4];
    const float* W2     = (const float*)d_in[5];
    const float* b2     = (const float*)d_in[6];
    const float* w_sig  = (const float*)d_in[7];
    const float* b_sig  = (const float*)d_in[8];
    const float* Wc1    = (const float*)d_in[9];
    const float* bc1    = (const float*)d_in[10];
    const float* Wc2    = (const float*)d_in[11];
    const float* bc2    = (const float*)d_in[12];

    float* out   = (float*)d_out;
    float* alpha = out + OFF_WEIGHTS;      // stash alpha in the weights slot
    float* rgb   = (float*)d_ws;           // [NR][NS][2] fp32

    dim3 blk(256);
    // 2048 blocks * 4 waves * 6 tiles * 64 samples = 4096*768 samples
    hipLaunchKernelGGL(mlp_mfma_kernel, dim3(2048), blk, 0, stream,
                       rays_o, rays_d, timev, W1, b1, W2, b2, w_sig, b_sig,
                       Wc1, bc1, Wc2, bc2, alpha, rgb);

    hipLaunchKernelGGL(composite_kernel, dim3((NR*64)/256), blk, 0, stream, rgb, out);
}